// Round 1
// baseline (45.200 us; speedup 1.0000x reference)
//
#include <hip/hip_runtime.h>
#include <math.h>

// Shapes (fixed by setup_inputs): B=4, T=64, d=128, L=32, H=32
#define N_TOK 256            // B*T
#define D     128
#define L_DIM 32
#define H_DIM 32
#define NROWS (N_TOK * D)    // 32768
#define NCH   8              // n's per score block
#define NCHUNKS (N_TOK / NCH) // 32

// ---------------------------------------------------------------------------
// K1: pa'[row,h] = b1[h] + sum_l z[row,l]*W1[h,l]        (W1a = W1[:, :32])
//     pb [row,h] =         sum_l z[row,l]*W1[h,32+l]     (W1b = W1[:, 32:])
// row = n*128 + i. 8 rows per 256-thread block.
// ---------------------------------------------------------------------------
__global__ __launch_bounds__(256) void pab_kernel(
    const float* __restrict__ z, const float* __restrict__ W1,
    const float* __restrict__ b1, float* __restrict__ pa,
    float* __restrict__ pb)
{
    __shared__ float sW1a[H_DIM][33];   // +1 pad: bank = (h+l)%32, conflict-free
    __shared__ float sW1b[H_DIM][33];
    __shared__ float sz[8][L_DIM];
    __shared__ float sb1[H_DIM];

    const int t = threadIdx.x;
    for (int f = t; f < H_DIM * 2 * L_DIM; f += 256) {
        int h = f >> 6, c = f & 63;
        float v = W1[f];
        if (c < L_DIM) sW1a[h][c] = v; else sW1b[h][c - L_DIM] = v;
    }
    if (t < H_DIM) sb1[t] = b1[t];

    const int r    = t >> 5;        // local row 0..7
    const int h    = t & 31;
    const int row0 = blockIdx.x * 8;
    sz[r][h] = z[(row0 + r) * L_DIM + h];
    __syncthreads();

    float accA = sb1[h];
    float accB = 0.f;
    #pragma unroll
    for (int l = 0; l < L_DIM; ++l) {
        float zv = sz[r][l];
        accA = fmaf(zv, sW1a[h][l], accA);
        accB = fmaf(zv, sW1b[h][l], accB);
    }
    const int row = row0 + r;
    pa[row * H_DIM + h] = accA;
    pb[row * H_DIM + h] = accB;
}

// ---------------------------------------------------------------------------
// K2 (hot): Spart[nc, i, j] = sum_{n in chunk} sum_h relu(pa'[n,i,h]+pb[n,j,h]) * W2[h]
// grid = (16 ij-tiles of 32x32, 32 n-chunks); block = 256 threads, 2x2 per thread.
// ---------------------------------------------------------------------------
__global__ __launch_bounds__(256) void scores_kernel(
    const float* __restrict__ pa, const float* __restrict__ pb,
    const float* __restrict__ W2, float* __restrict__ Spart)
{
    // pad rows to 36 floats: float4-aligned; pb read = 2-way bank alias (free)
    __shared__ float spa[NCH][32][36];
    __shared__ float spb[NCH][32][36];

    const int t  = threadIdx.x;
    const int i0 = (blockIdx.x & 3) * 32;
    const int j0 = (blockIdx.x >> 2) * 32;
    const int nc = blockIdx.y;

    // stage: 2048 float4 per buffer, fully coalesced (h4 fast, row slow)
    for (int f = t; f < NCH * 32 * 8; f += 256) {
        int h4   = f & 7;
        int ridx = f >> 3;
        int nn   = ridx >> 5;
        int ii   = ridx & 31;
        int n    = nc * NCH + nn;
        float4 va = *(const float4*)&pa[(n * D + i0 + ii) * H_DIM + h4 * 4];
        float4 vb = *(const float4*)&pb[(n * D + j0 + ii) * H_DIM + h4 * 4];
        *(float4*)&spa[nn][ii][h4 * 4] = va;
        *(float4*)&spb[nn][ii][h4 * 4] = vb;
    }

    float w2r[H_DIM];             // uniform -> compiler scalarizes to SGPRs
    #pragma unroll
    for (int hh = 0; hh < H_DIM; ++hh) w2r[hh] = W2[hh];
    __syncthreads();

    const int tj = t & 15;
    const int ti = t >> 4;
    float acc00 = 0.f, acc01 = 0.f, acc10 = 0.f, acc11 = 0.f;

    for (int nn = 0; nn < NCH; ++nn) {
        const float* pA0 = &spa[nn][ti][0];
        const float* pA1 = &spa[nn][ti + 16][0];
        const float* pB0 = &spb[nn][tj][0];
        const float* pB1 = &spb[nn][tj + 16][0];
        #pragma unroll
        for (int k = 0; k < 8; ++k) {
            float4 A0 = *(const float4*)(pA0 + k * 4);
            float4 A1 = *(const float4*)(pA1 + k * 4);
            float4 B0 = *(const float4*)(pB0 + k * 4);
            float4 B1 = *(const float4*)(pB1 + k * 4);
            const float* fa0 = (const float*)&A0;
            const float* fa1 = (const float*)&A1;
            const float* fb0 = (const float*)&B0;
            const float* fb1 = (const float*)&B1;
            #pragma unroll
            for (int c = 0; c < 4; ++c) {
                float w = w2r[4 * k + c];
                acc00 = fmaf(fmaxf(fa0[c] + fb0[c], 0.f), w, acc00);
                acc01 = fmaf(fmaxf(fa0[c] + fb1[c], 0.f), w, acc01);
                acc10 = fmaf(fmaxf(fa1[c] + fb0[c], 0.f), w, acc10);
                acc11 = fmaf(fmaxf(fa1[c] + fb1[c], 0.f), w, acc11);
            }
        }
    }

    float* Sp = Spart + nc * (D * D);
    Sp[(i0 + ti)      * D + (j0 + tj)]      = acc00;
    Sp[(i0 + ti)      * D + (j0 + tj + 16)] = acc01;
    Sp[(i0 + ti + 16) * D + (j0 + tj)]      = acc10;
    Sp[(i0 + ti + 16) * D + (j0 + tj + 16)] = acc11;
}

// ---------------------------------------------------------------------------
// K3: reduce partials, antisymmetrize, sigmoids, Wm. b2 cancels exactly.
// out[0:16384] = A, out[16384:32768] = Wm.
// ---------------------------------------------------------------------------
__global__ __launch_bounds__(256) void finalize_kernel(
    const float* __restrict__ Spart, const float* __restrict__ Wmag,
    float* __restrict__ out)
{
    const int t = blockIdx.x * 256 + threadIdx.x;   // 0..16383
    const int i = t >> 7, j = t & 127;

    float sij = 0.f, sji = 0.f;
    #pragma unroll 4
    for (int c = 0; c < NCHUNKS; ++c) {
        sij += Spart[c * (D * D) + i * D + j];
        sji += Spart[c * (D * D) + j * D + i];
    }
    float a   = (sij - sji) * (1.0f / 256.0f);      // mean over n; TAU = 1
    float dir = 1.0f / (1.0f + expf(-a));
    float wm  = 0.5f * (Wmag[i * D + j] + Wmag[j * D + i]);
    float A;
    if (i == j) { wm = 0.f; A = 0.f; }
    else        { A = dir / (1.0f + expf(-wm)); }
    out[t]         = A;
    out[D * D + t] = wm;
}

extern "C" void kernel_launch(void* const* d_in, const int* in_sizes, int n_in,
                              void* d_out, int out_size, void* d_ws, size_t ws_size,
                              hipStream_t stream)
{
    const float* z    = (const float*)d_in[0];   // (4,64,128,32)
    const float* Wmag = (const float*)d_in[1];   // (128,128)
    const float* W1   = (const float*)d_in[2];   // (32,64)
    const float* b1   = (const float*)d_in[3];   // (32,)
    const float* W2   = (const float*)d_in[4];   // (1,32)
    // d_in[5] = b2: cancels in scores - scores^T, unused.

    float* pa = (float*)d_ws;                    // 32768*32 f32 = 4 MB
    float* pb = pa + NROWS * H_DIM;              // 4 MB
    float* Sp = pb + NROWS * H_DIM;              // 32*16384 f32 = 2 MB
    float* out = (float*)d_out;

    pab_kernel<<<NROWS / 8, 256, 0, stream>>>(z, W1, b1, pa, pb);
    scores_kernel<<<dim3(16, NCHUNKS), 256, 0, stream>>>(pa, pb, W2, Sp);
    finalize_kernel<<<(D * D) / 256, 256, 0, stream>>>(Sp, Wmag, out);
}

// Round 2
// 41.057 us; speedup vs baseline: 1.1009x; 1.1009x over previous
//
#include <hip/hip_runtime.h>
#include <math.h>

#define D     128
#define NT    256            // B*T
#define HD    32
#define LD    32
#define NCH   4              // n's per score block
#define NC    (NT/NCH)       // 64 chunks
#define NROWS (NT*D)         // 32768

// ---------------------------------------------------------------------------
// K1: pa[row][h] = b1[h] + z[row]·W1a[h,:],  pb[row][h] = z[row]·W1b[h,:]
// 32 rows per block, 1024 blocks.
// ---------------------------------------------------------------------------
__global__ __launch_bounds__(256) void pab_kernel(
    const float* __restrict__ z, const float* __restrict__ W1,
    const float* __restrict__ b1, float* __restrict__ pa,
    float* __restrict__ pb)
{
    __shared__ float sW1a[HD][33];   // (h+l)%32 banks: conflict-free
    __shared__ float sW1b[HD][33];
    __shared__ float sz[32][33];
    __shared__ float sb1[HD];

    const int t = threadIdx.x;
    for (int f = t; f < HD * 2 * LD; f += 256) {
        int h = f >> 6, c = f & 63;
        float v = W1[f];
        if (c < LD) sW1a[h][c] = v; else sW1b[h][c - LD] = v;
    }
    if (t < HD) sb1[t] = b1[t];
    const int row0 = blockIdx.x * 32;
    for (int f = t; f < 32 * LD; f += 256)
        sz[f >> 5][f & 31] = z[row0 * LD + f];
    __syncthreads();

    #pragma unroll
    for (int q = 0; q < 4; ++q) {
        int idx = t + q * 256;           // 1024 (row,h) pairs
        int r = idx >> 5, h = idx & 31;
        float aA = sb1[h], aB = 0.f;
        #pragma unroll
        for (int l = 0; l < LD; ++l) {
            float zv = sz[r][l];
            aA = fmaf(zv, sW1a[h][l], aA);
            aB = fmaf(zv, sW1b[h][l], aB);
        }
        pa[(row0 + r) * HD + h] = aA;
        pb[(row0 + r) * HD + h] = aB;
    }
}

// ---------------------------------------------------------------------------
// K2 (hot): per block: 64x64 (i,j) tile, NCH n's. 512 thr = 8 waves.
// lane = i (pa row in 32 VGPRs); j wave-uniform (broadcast ds_read of pb).
// Writes S partials both orientations, all coalesced.
// ---------------------------------------------------------------------------
__global__ __launch_bounds__(512) void scores_kernel(
    const float* __restrict__ pa, const float* __restrict__ pb,
    const float* __restrict__ W2, float* __restrict__ Spart,
    float* __restrict__ SpartT)
{
    __shared__ float spa[NCH][64][36];   // pad 36: (4*lane+4k)%32 -> 8-way (b128 optimum)
    __shared__ float spb[NCH][64][HD];   // uniform reads: no conflicts, keep linear
    __shared__ float sS[64][65];         // pad 65: (lane+col)%32 conflict-free

    const int t  = threadIdx.x;
    const int i0 = (blockIdx.x & 1) * 64;
    const int j0 = (blockIdx.x >> 1) * 64;
    const int nc = blockIdx.y;

    // stage pa/pb tiles: 2048 float4 each, coalesced
    for (int f = t; f < NCH * 64 * 8; f += 512) {
        int h4 = f & 7, row = (f >> 3) & 63, nn = f >> 9;
        int n = nc * NCH + nn;
        float4 va = *(const float4*)&pa[((n * D) + i0 + row) * HD + h4 * 4];
        float4 vb = *(const float4*)&pb[((n * D) + j0 + row) * HD + h4 * 4];
        *(float4*)&spa[nn][row][h4 * 4] = va;
        *(float4*)&spb[nn][row][h4 * 4] = vb;
    }

    float w2r[HD];                        // uniform addr -> s_loads
    #pragma unroll
    for (int h = 0; h < HD; ++h) w2r[h] = W2[h];

    __syncthreads();

    const int lane = t & 63;
    const int jb   = __builtin_amdgcn_readfirstlane((t >> 6) * 8);

    float acc[8];
    #pragma unroll
    for (int jj = 0; jj < 8; ++jj) acc[jj] = 0.f;

    #pragma unroll 1
    for (int nn = 0; nn < NCH; ++nn) {
        float par[HD];                    // this lane's pa row
        #pragma unroll
        for (int k = 0; k < 8; ++k)
            *(float4*)&par[k * 4] = *(const float4*)&spa[nn][lane][k * 4];
        #pragma unroll
        for (int jj = 0; jj < 8; ++jj) {
            float pbv[HD];                // wave-uniform pb row (broadcast reads)
            #pragma unroll
            for (int k = 0; k < 8; ++k)
                *(float4*)&pbv[k * 4] = *(const float4*)&spb[nn][jb + jj][k * 4];
            float a = acc[jj];
            #pragma unroll
            for (int h = 0; h < HD; ++h)
                a = fmaf(w2r[h], fmaxf(par[h] + pbv[h], 0.f), a);
            acc[jj] = a;
        }
    }

    // copy 1: SpartT[nc][j][i] = S[i][j] — lanes = consecutive i: coalesced
    {
        float* SpT = SpartT + ((size_t)nc * D + j0 + jb) * D + i0;
        #pragma unroll
        for (int jj = 0; jj < 8; ++jj)
            SpT[jj * D + lane] = acc[jj];
    }
    // copy 2: Spart[nc][i][j] = S[i][j] via LDS transpose, coalesced
    #pragma unroll
    for (int jj = 0; jj < 8; ++jj)
        sS[lane][jb + jj] = acc[jj];
    __syncthreads();
    {
        int ir = t >> 3;                  // 0..63
        int jc = (t & 7) * 8;             // 0..56
        float v[8];
        #pragma unroll
        for (int k = 0; k < 8; ++k) v[k] = sS[ir][jc + k];
        float* Sp = Spart + ((size_t)nc * D + i0 + ir) * D + j0 + jc;
        *(float4*)&Sp[0] = make_float4(v[0], v[1], v[2], v[3]);
        *(float4*)&Sp[4] = make_float4(v[4], v[5], v[6], v[7]);
    }
}

// ---------------------------------------------------------------------------
// K3: fully-coalesced reduce of both orientations + antisym/sigmoid/Wm.
// b2 cancels exactly in S - S^T.
// ---------------------------------------------------------------------------
__global__ __launch_bounds__(256) void finalize_kernel(
    const float* __restrict__ Spart, const float* __restrict__ SpartT,
    const float* __restrict__ Wmag, float* __restrict__ out)
{
    const int t = blockIdx.x * 256 + threadIdx.x;   // 0..16383
    const int i = t >> 7, j = t & 127;

    float s0 = 0.f, s1 = 0.f, s2 = 0.f, s3 = 0.f;
    #pragma unroll 4
    for (int nc = 0; nc < NC; nc += 2) {
        s0 += Spart [nc * D * D + t];       // S[i][j] partial
        s1 += SpartT[nc * D * D + t];       // S[j][i] partial
        s2 += Spart [(nc + 1) * D * D + t];
        s3 += SpartT[(nc + 1) * D * D + t];
    }
    float a   = ((s0 + s2) - (s1 + s3)) * (1.0f / 256.0f);  // mean over n; TAU=1
    float dir = 1.0f / (1.0f + __expf(-a));
    float wm  = 0.5f * (Wmag[i * D + j] + Wmag[j * D + i]);
    float A;
    if (i == j) { wm = 0.f; A = 0.f; }
    else        { A = dir / (1.0f + __expf(-wm)); }
    out[t]         = A;
    out[D * D + t] = wm;
}

extern "C" void kernel_launch(void* const* d_in, const int* in_sizes, int n_in,
                              void* d_out, int out_size, void* d_ws, size_t ws_size,
                              hipStream_t stream)
{
    const float* z    = (const float*)d_in[0];   // (4,64,128,32)
    const float* Wmag = (const float*)d_in[1];   // (128,128)
    const float* W1   = (const float*)d_in[2];   // (32,64)
    const float* b1   = (const float*)d_in[3];   // (32,)
    const float* W2   = (const float*)d_in[4];   // (1,32)
    // d_in[5] = b2: cancels in scores - scores^T.

    float* pa     = (float*)d_ws;                 // 1,048,576 f32 = 4 MB
    float* pb     = pa + (size_t)NROWS * HD;      // 4 MB
    float* Spart  = pb + (size_t)NROWS * HD;      // NC*D*D = 4 MB
    float* SpartT = Spart + (size_t)NC * D * D;   // 4 MB
    float* out    = (float*)d_out;

    pab_kernel<<<NROWS / 32, 256, 0, stream>>>(z, W1, b1, pa, pb);
    scores_kernel<<<dim3(4, NC), 512, 0, stream>>>(pa, pb, W2, Spart, SpartT);
    finalize_kernel<<<(D * D) / 256, 256, 0, stream>>>(Spart, SpartT, Wmag, out);
}